// Round 3
// baseline (871.830 us; speedup 1.0000x reference)
//
#include <hip/hip_runtime.h>

typedef __attribute__((ext_vector_type(4))) float f32x4;
typedef __attribute__((ext_vector_type(8))) short s16x8;
typedef __attribute__((ext_vector_type(4))) int i32x4;
typedef __attribute__((ext_vector_type(4))) unsigned short u16x4;

#define NEG_INF_F (-9.0e15f)
#define LOG2E_F 1.44269504088896340736f
#define N_ROWS 8192
#define F_DIM 256

__device__ __forceinline__ unsigned short f2bf(float f) {
    unsigned int u = __builtin_bit_cast(unsigned int, f);
    u += 0x7fffu + ((u >> 16) & 1u);   // round-to-nearest-even
    return (unsigned short)(u >> 16);
}

// ------------- Kernel 1: h = x @ W^T (f32) ; hT = bf16(h)^T --------------
__global__ __launch_bounds__(256) void k1_gemm(const float* __restrict__ x,
                                               const float* __restrict__ W,
                                               float* __restrict__ h,
                                               unsigned short* __restrict__ hT) {
    __shared__ float xT[128][64];
    __shared__ float wT[128][64];
    const int tid = threadIdx.x;
    const int rb = blockIdx.x >> 2, fbk = blockIdx.x & 3;
    const int row0 = rb * 64, f0 = fbk * 64;
    const int rs = tid >> 2, cs = tid & 3;
    const int r0 = (tid & 15) * 4, fc = (tid >> 4) * 4;
    float acc[4][4];
#pragma unroll
    for (int i = 0; i < 4; ++i)
#pragma unroll
        for (int j = 0; j < 4; ++j) acc[i][j] = 0.0f;

#pragma unroll 1
    for (int p = 0; p < 2; ++p) {
        const int kb = p * 128;
        if (p) __syncthreads();
        const float* xrow = x + (size_t)(row0 + rs) * F_DIM + kb + cs * 32;
        const float* wrow = W + (size_t)(f0 + rs) * F_DIM + kb + cs * 32;
#pragma unroll
        for (int i = 0; i < 8; ++i) {
            f32x4 xv = *(const f32x4*)(xrow + i * 4);
            f32x4 wv = *(const f32x4*)(wrow + i * 4);
#pragma unroll
            for (int jj = 0; jj < 4; ++jj) {
                xT[cs * 32 + i * 4 + jj][rs] = xv[jj];
                wT[cs * 32 + i * 4 + jj][rs] = wv[jj];
            }
        }
        __syncthreads();
#pragma unroll 4
        for (int kk = 0; kk < 128; ++kk) {
            f32x4 xv = *(const f32x4*)&xT[kk][r0];
            f32x4 wv = *(const f32x4*)&wT[kk][fc];
#pragma unroll
            for (int i = 0; i < 4; ++i)
#pragma unroll
                for (int j = 0; j < 4; ++j)
                    acc[i][j] = fmaf(xv[i], wv[j], acc[i][j]);
        }
    }
#pragma unroll
    for (int i = 0; i < 4; ++i) {
        f32x4 hv;
        hv[0] = acc[i][0]; hv[1] = acc[i][1]; hv[2] = acc[i][2]; hv[3] = acc[i][3];
        *(f32x4*)(h + (size_t)(row0 + r0 + i) * F_DIM + f0 + fc) = hv;
    }
#pragma unroll
    for (int j = 0; j < 4; ++j) {
        u16x4 t;
        t[0] = f2bf(acc[0][j]); t[1] = f2bf(acc[1][j]);
        t[2] = f2bf(acc[2][j]); t[3] = f2bf(acc[3][j]);
        *(u16x4*)(hT + (size_t)(f0 + fc + j) * N_ROWS + row0 + r0) = t;
    }
}

// ------------- Kernel 1b: s1 = h@a1, s2 = h@a2 (f32) ---------------------
__global__ __launch_bounds__(256) void k1b_s(const float* __restrict__ h,
                                             const float* __restrict__ a,
                                             float* __restrict__ s1,
                                             float* __restrict__ s2) {
    const int tid = threadIdx.x, lane = tid & 63, w = tid >> 6;
    f32x4 a1 = *(const f32x4*)(a + lane * 4);
    f32x4 a2 = *(const f32x4*)(a + 256 + lane * 4);
    const int row0 = blockIdx.x * 32 + w * 8;
#pragma unroll 1
    for (int rr = 0; rr < 8; ++rr) {
        const int row = row0 + rr;
        f32x4 hv = *(const f32x4*)(h + (size_t)row * F_DIM + lane * 4);
        float p1 = hv[0] * a1[0] + hv[1] * a1[1] + hv[2] * a1[2] + hv[3] * a1[3];
        float p2 = hv[0] * a2[0] + hv[1] * a2[1] + hv[2] * a2[2] + hv[3] * a2[3];
#pragma unroll
        for (int o = 32; o; o >>= 1) { p1 += __shfl_xor(p1, o); p2 += __shfl_xor(p2, o); }
        if (lane == 0) { s1[row] = p1; s2[row] = p2; }
    }
}

// ------------- Kernel 2: fused masked softmax + PV -----------------------
__device__ __forceinline__ void k2_step(i32x4 q0, i32x4 q1, i32x4 q2, i32x4 q3,
                                        int k0, int lane15, int kg, int koff, int fb,
                                        float si,
                                        const unsigned short* __restrict__ hT,
                                        const float* __restrict__ s2,
                                        f32x4* __restrict__ acc,
                                        float& m_run, float& l_run) {
    s16x8 bfr0[8], bfr1[8];
#pragma unroll
    for (int nt = 0; nt < 8; ++nt) {
        const size_t rbase = (size_t)(fb + nt * 16 + lane15) * N_ROWS;
        bfr0[nt] = *(const s16x8*)(hT + rbase + k0 + koff);
        bfr1[nt] = *(const s16x8*)(hT + rbase + k0 + 32 + koff);
    }
    f32x4 sv0 = *(const f32x4*)(s2 + k0 + koff);
    f32x4 sv1 = *(const f32x4*)(s2 + k0 + koff + 4);
    f32x4 sv2 = *(const f32x4*)(s2 + k0 + 32 + koff);
    f32x4 sv3 = *(const f32x4*)(s2 + k0 + 32 + koff + 4);

    float ev[16];
#pragma unroll
    for (int j = 0; j < 4; ++j) {
        float t0 = si + sv0[j]; t0 = fmaxf(t0, 0.2f * t0); ev[j]      = (q0[j] > 0) ? t0 : NEG_INF_F;
        float t1 = si + sv1[j]; t1 = fmaxf(t1, 0.2f * t1); ev[4 + j]  = (q1[j] > 0) ? t1 : NEG_INF_F;
        float t2 = si + sv2[j]; t2 = fmaxf(t2, 0.2f * t2); ev[8 + j]  = (q2[j] > 0) ? t2 : NEG_INF_F;
        float t3 = si + sv3[j]; t3 = fmaxf(t3, 0.2f * t3); ev[12 + j] = (q3[j] > 0) ? t3 : NEG_INF_F;
    }
    float tm = ev[0];
#pragma unroll
    for (int i = 1; i < 16; ++i) tm = fmaxf(tm, ev[i]);
    tm = fmaxf(tm, __shfl_xor(tm, 16));
    tm = fmaxf(tm, __shfl_xor(tm, 32));
    const float m_new = fmaxf(m_run, tm);
    const bool upd = m_new > m_run;
    const float sc = exp2f((m_run - m_new) * LOG2E_F);
    float pv[16];
    float ts = 0.0f;
#pragma unroll
    for (int i = 0; i < 16; ++i) { pv[i] = exp2f((ev[i] - m_new) * LOG2E_F); ts += pv[i]; }
    ts += __shfl_xor(ts, 16);
    ts += __shfl_xor(ts, 32);
    l_run = l_run * sc + ts;
    m_run = m_new;
    if (__any(upd)) {
#pragma unroll
        for (int r = 0; r < 4; ++r) {
            const float scr = __shfl(sc, kg * 4 + r);
#pragma unroll
            for (int nt = 0; nt < 8; ++nt) acc[nt][r] *= scr;
        }
    }
    s16x8 af0, af1;
#pragma unroll
    for (int j = 0; j < 8; ++j) { af0[j] = (short)f2bf(pv[j]); af1[j] = (short)f2bf(pv[8 + j]); }
#pragma unroll
    for (int nt = 0; nt < 8; ++nt)
        acc[nt] = __builtin_amdgcn_mfma_f32_16x16x32_bf16(af0, bfr0[nt], acc[nt], 0, 0, 0);
#pragma unroll
    for (int nt = 0; nt < 8; ++nt)
        acc[nt] = __builtin_amdgcn_mfma_f32_16x16x32_bf16(af1, bfr1[nt], acc[nt], 0, 0, 0);
}

// grid 512 blocks x 16 rows; 8 waves/block = 2(feat) x 4(key-split).
// 2 blocks/CU (launch_bounds(512,4) -> VGPR cap 128, no spill) = 4 waves/SIMD.
__global__ __launch_bounds__(512, 4) void k2_attn(const int* __restrict__ adj,
                                                  const unsigned short* __restrict__ hT,
                                                  const float* __restrict__ s1,
                                                  const float* __restrict__ s2,
                                                  float* __restrict__ out) {
    __shared__ float mlbuf[2][4][16];           // [m|l][wk][row]
    __shared__ float accbuf[2][16][132];        // [wn][row][feat] (+4 pad)

    const int tid = threadIdx.x;
    const int lane = tid & 63;
    const int wvi = tid >> 6;                   // 0..7
    const int wn = wvi & 1, wk = wvi >> 1;      // wk 0..3
    const int lane15 = lane & 15, kg = lane >> 4, koff = kg * 8;
    const int row0 = (int)blockIdx.x * 16;
    const int mrow = row0 + lane15;
    const int fb = wn * 128;
    const int kbase = wk * 2048;                // each wave owns 2048 keys
    const float si = s1[mrow];
    const int* __restrict__ arow = adj + (size_t)mrow * N_ROWS;

    f32x4 acc[8];
#pragma unroll
    for (int nt = 0; nt < 8; ++nt) { f32x4 z = {0.f, 0.f, 0.f, 0.f}; acc[nt] = z; }
    float m_run = NEG_INF_F, l_run = 0.0f;

    i32x4 A0, A1, A2, A3, B0, B1, B2, B3;
    A0 = *(const i32x4*)(arow + kbase + koff);
    A1 = *(const i32x4*)(arow + kbase + koff + 4);
    A2 = *(const i32x4*)(arow + kbase + 32 + koff);
    A3 = *(const i32x4*)(arow + kbase + 32 + koff + 4);

#pragma unroll 1
    for (int it = 0; it < 16; ++it) {
        const int k0 = kbase + it * 128;
        {   // prefetch keys [k0+64, k0+128)
            const int kp = k0 + 64;
            B0 = *(const i32x4*)(arow + kp + koff);
            B1 = *(const i32x4*)(arow + kp + koff + 4);
            B2 = *(const i32x4*)(arow + kp + 32 + koff);
            B3 = *(const i32x4*)(arow + kp + 32 + koff + 4);
        }
        k2_step(A0, A1, A2, A3, k0, lane15, kg, koff, fb, si, hT, s2, acc, m_run, l_run);
        {   // prefetch next iteration's first half (clamped on last iter)
            const int kp = (it == 15) ? kbase : (k0 + 128);
            A0 = *(const i32x4*)(arow + kp + koff);
            A1 = *(const i32x4*)(arow + kp + koff + 4);
            A2 = *(const i32x4*)(arow + kp + 32 + koff);
            A3 = *(const i32x4*)(arow + kp + 32 + koff + 4);
        }
        k2_step(B0, B1, B2, B3, k0 + 64, lane15, kg, koff, fb, si, hT, s2, acc, m_run, l_run);
    }

    // ---- split-K merge (flash combine) ----
    if (wn == 0 && kg == 0) {                   // m/l identical across wn; rows 0..15
        mlbuf[0][wk][lane15] = m_run;
        mlbuf[1][wk][lane15] = l_run;
    }
    __syncthreads();

    float myscale[4], linv[4];
#pragma unroll
    for (int r = 0; r < 4; ++r) {
        const int dr = kg * 4 + r;              // D-layout row this lane owns
        const float m0 = mlbuf[0][0][dr], m1 = mlbuf[0][1][dr];
        const float m2 = mlbuf[0][2][dr], m3 = mlbuf[0][3][dr];
        const float ms = fmaxf(fmaxf(m0, m1), fmaxf(m2, m3));
        const float e0 = exp2f((m0 - ms) * LOG2E_F);
        const float e1 = exp2f((m1 - ms) * LOG2E_F);
        const float e2 = exp2f((m2 - ms) * LOG2E_F);
        const float e3 = exp2f((m3 - ms) * LOG2E_F);
        const float ls = e0 * mlbuf[1][0][dr] + e1 * mlbuf[1][1][dr]
                       + e2 * mlbuf[1][2][dr] + e3 * mlbuf[1][3][dr];
        const float mo = mlbuf[0][wk][dr];      // own max (LDS read, no runtime reg index)
        myscale[r] = exp2f((mo - ms) * LOG2E_F);
        linv[r] = 1.0f / ls;
    }
#pragma unroll
    for (int r = 0; r < 4; ++r)
#pragma unroll
        for (int nt = 0; nt < 8; ++nt) acc[nt][r] *= myscale[r];

#pragma unroll 1
    for (int s = 1; s < 4; ++s) {
        if (wk == s) {
#pragma unroll
            for (int r = 0; r < 4; ++r)
#pragma unroll
                for (int nt = 0; nt < 8; ++nt)
                    accbuf[wn][kg * 4 + r][nt * 16 + lane15] = acc[nt][r];
        }
        __syncthreads();
        if (wk == 0) {
#pragma unroll
            for (int r = 0; r < 4; ++r)
#pragma unroll
                for (int nt = 0; nt < 8; ++nt)
                    acc[nt][r] += accbuf[wn][kg * 4 + r][nt * 16 + lane15];
        }
        __syncthreads();
    }

    if (wk == 0) {
#pragma unroll
        for (int r = 0; r < 4; ++r) {
            const int orow = row0 + kg * 4 + r;
            float* orow_p = out + (size_t)orow * F_DIM + fb + lane15;
#pragma unroll
            for (int nt = 0; nt < 8; ++nt) orow_p[nt * 16] = acc[nt][r] * linv[r];
        }
    }
}

extern "C" void kernel_launch(void* const* d_in, const int* in_sizes, int n_in,
                              void* d_out, int out_size, void* d_ws, size_t ws_size,
                              hipStream_t stream) {
    (void)in_sizes; (void)n_in; (void)out_size; (void)ws_size;
    const float* x  = (const float*)d_in[0];
    const int*  adj = (const int*)d_in[1];
    const float* W  = (const float*)d_in[2];
    const float* a  = (const float*)d_in[3];
    float* out = (float*)d_out;
    char* ws = (char*)d_ws;
    unsigned short* hT = (unsigned short*)ws;               // 4 MB  [256][8192] bf16
    float* h  = (float*)(ws + (4 << 20));                   // 8 MB  [8192][256] f32
    float* s1 = (float*)(ws + (12 << 20));                  // 32 KB
    float* s2 = (float*)(ws + (12 << 20) + 32768);          // 32 KB

    k1_gemm<<<512, 256, 0, stream>>>(x, W, h, hT);
    k1b_s<<<256, 256, 0, stream>>>(h, a, s1, s2);
    k2_attn<<<512, 512, 0, stream>>>(adj, hT, s1, s2, out);
}

// Round 4
// 339.352 us; speedup vs baseline: 2.5691x; 2.5691x over previous
//
#include <hip/hip_runtime.h>

typedef __attribute__((ext_vector_type(4))) float f32x4;
typedef __attribute__((ext_vector_type(8))) short s16x8;
typedef __attribute__((ext_vector_type(4))) int i32x4;
typedef __attribute__((ext_vector_type(4))) unsigned short u16x4;

#define NEG_INF_F (-9.0e15f)
#define LOG2E_F 1.44269504088896340736f
#define N_ROWS 8192
#define F_DIM 256

__device__ __forceinline__ unsigned short f2bf(float f) {
    unsigned int u = __builtin_bit_cast(unsigned int, f);
    u += 0x7fffu + ((u >> 16) & 1u);   // round-to-nearest-even
    return (unsigned short)(u >> 16);
}

// ------------- Kernel 1: h = x @ W^T (f32) ; hT = bf16(h)^T --------------
__global__ __launch_bounds__(256) void k1_gemm(const float* __restrict__ x,
                                               const float* __restrict__ W,
                                               float* __restrict__ h,
                                               unsigned short* __restrict__ hT) {
    __shared__ float xT[128][64];
    __shared__ float wT[128][64];
    const int tid = threadIdx.x;
    const int rb = blockIdx.x >> 2, fbk = blockIdx.x & 3;
    const int row0 = rb * 64, f0 = fbk * 64;
    const int rs = tid >> 2, cs = tid & 3;
    const int r0 = (tid & 15) * 4, fc = (tid >> 4) * 4;
    float acc[4][4];
#pragma unroll
    for (int i = 0; i < 4; ++i)
#pragma unroll
        for (int j = 0; j < 4; ++j) acc[i][j] = 0.0f;

#pragma unroll 1
    for (int p = 0; p < 2; ++p) {
        const int kb = p * 128;
        if (p) __syncthreads();
        const float* xrow = x + (size_t)(row0 + rs) * F_DIM + kb + cs * 32;
        const float* wrow = W + (size_t)(f0 + rs) * F_DIM + kb + cs * 32;
#pragma unroll
        for (int i = 0; i < 8; ++i) {
            f32x4 xv = *(const f32x4*)(xrow + i * 4);
            f32x4 wv = *(const f32x4*)(wrow + i * 4);
#pragma unroll
            for (int jj = 0; jj < 4; ++jj) {
                xT[cs * 32 + i * 4 + jj][rs] = xv[jj];
                wT[cs * 32 + i * 4 + jj][rs] = wv[jj];
            }
        }
        __syncthreads();
#pragma unroll 4
        for (int kk = 0; kk < 128; ++kk) {
            f32x4 xv = *(const f32x4*)&xT[kk][r0];
            f32x4 wv = *(const f32x4*)&wT[kk][fc];
#pragma unroll
            for (int i = 0; i < 4; ++i)
#pragma unroll
                for (int j = 0; j < 4; ++j)
                    acc[i][j] = fmaf(xv[i], wv[j], acc[i][j]);
        }
    }
#pragma unroll
    for (int i = 0; i < 4; ++i) {
        f32x4 hv;
        hv[0] = acc[i][0]; hv[1] = acc[i][1]; hv[2] = acc[i][2]; hv[3] = acc[i][3];
        *(f32x4*)(h + (size_t)(row0 + r0 + i) * F_DIM + f0 + fc) = hv;
    }
#pragma unroll
    for (int j = 0; j < 4; ++j) {
        u16x4 t;
        t[0] = f2bf(acc[0][j]); t[1] = f2bf(acc[1][j]);
        t[2] = f2bf(acc[2][j]); t[3] = f2bf(acc[3][j]);
        *(u16x4*)(hT + (size_t)(f0 + fc + j) * N_ROWS + row0 + r0) = t;
    }
}

// ------------- Kernel 1b: s1 = h@a1, s2 = h@a2 (f32) ---------------------
__global__ __launch_bounds__(256) void k1b_s(const float* __restrict__ h,
                                             const float* __restrict__ a,
                                             float* __restrict__ s1,
                                             float* __restrict__ s2) {
    const int tid = threadIdx.x, lane = tid & 63, w = tid >> 6;
    f32x4 a1 = *(const f32x4*)(a + lane * 4);
    f32x4 a2 = *(const f32x4*)(a + 256 + lane * 4);
    const int row0 = blockIdx.x * 32 + w * 8;
#pragma unroll 1
    for (int rr = 0; rr < 8; ++rr) {
        const int row = row0 + rr;
        f32x4 hv = *(const f32x4*)(h + (size_t)row * F_DIM + lane * 4);
        float p1 = hv[0] * a1[0] + hv[1] * a1[1] + hv[2] * a1[2] + hv[3] * a1[3];
        float p2 = hv[0] * a2[0] + hv[1] * a2[1] + hv[2] * a2[2] + hv[3] * a2[3];
#pragma unroll
        for (int o = 32; o; o >>= 1) { p1 += __shfl_xor(p1, o); p2 += __shfl_xor(p2, o); }
        if (lane == 0) { s1[row] = p1; s2[row] = p2; }
    }
}

// ------------- Kernel 2: fused masked softmax + PV (partial) -------------
__device__ __forceinline__ void k2_step(i32x4 q0, i32x4 q1, i32x4 q2, i32x4 q3,
                                        int k0, int lane15, int kg, int koff, int fb,
                                        float si,
                                        const unsigned short* __restrict__ hT,
                                        const float* __restrict__ s2,
                                        f32x4* __restrict__ acc,
                                        float& m_run, float& l_run) {
    s16x8 bfr0[8], bfr1[8];
#pragma unroll
    for (int nt = 0; nt < 8; ++nt) {
        const size_t rbase = (size_t)(fb + nt * 16 + lane15) * N_ROWS;
        bfr0[nt] = *(const s16x8*)(hT + rbase + k0 + koff);
        bfr1[nt] = *(const s16x8*)(hT + rbase + k0 + 32 + koff);
    }
    f32x4 sv0 = *(const f32x4*)(s2 + k0 + koff);
    f32x4 sv1 = *(const f32x4*)(s2 + k0 + koff + 4);
    f32x4 sv2 = *(const f32x4*)(s2 + k0 + 32 + koff);
    f32x4 sv3 = *(const f32x4*)(s2 + k0 + 32 + koff + 4);

    float ev[16];
#pragma unroll
    for (int j = 0; j < 4; ++j) {
        float t0 = si + sv0[j]; t0 = fmaxf(t0, 0.2f * t0); ev[j]      = (q0[j] > 0) ? t0 : NEG_INF_F;
        float t1 = si + sv1[j]; t1 = fmaxf(t1, 0.2f * t1); ev[4 + j]  = (q1[j] > 0) ? t1 : NEG_INF_F;
        float t2 = si + sv2[j]; t2 = fmaxf(t2, 0.2f * t2); ev[8 + j]  = (q2[j] > 0) ? t2 : NEG_INF_F;
        float t3 = si + sv3[j]; t3 = fmaxf(t3, 0.2f * t3); ev[12 + j] = (q3[j] > 0) ? t3 : NEG_INF_F;
    }
    float tm = ev[0];
#pragma unroll
    for (int i = 1; i < 16; ++i) tm = fmaxf(tm, ev[i]);
    tm = fmaxf(tm, __shfl_xor(tm, 16));
    tm = fmaxf(tm, __shfl_xor(tm, 32));
    const float m_new = fmaxf(m_run, tm);
    const bool upd = m_new > m_run;
    const float sc = exp2f((m_run - m_new) * LOG2E_F);
    float pv[16];
    float ts = 0.0f;
#pragma unroll
    for (int i = 0; i < 16; ++i) { pv[i] = exp2f((ev[i] - m_new) * LOG2E_F); ts += pv[i]; }
    ts += __shfl_xor(ts, 16);
    ts += __shfl_xor(ts, 32);
    l_run = l_run * sc + ts;
    m_run = m_new;
    if (__any(upd)) {
#pragma unroll
        for (int r = 0; r < 4; ++r) {
            const float scr = __shfl(sc, kg * 4 + r);
#pragma unroll
            for (int nt = 0; nt < 8; ++nt) acc[nt][r] *= scr;
        }
    }
    s16x8 af0, af1;
#pragma unroll
    for (int j = 0; j < 8; ++j) { af0[j] = (short)f2bf(pv[j]); af1[j] = (short)f2bf(pv[8 + j]); }
#pragma unroll
    for (int nt = 0; nt < 8; ++nt)
        acc[nt] = __builtin_amdgcn_mfma_f32_16x16x32_bf16(af0, bfr0[nt], acc[nt], 0, 0, 0);
#pragma unroll
    for (int nt = 0; nt < 8; ++nt)
        acc[nt] = __builtin_amdgcn_mfma_f32_16x16x32_bf16(af1, bfr1[nt], acc[nt], 0, 0, 0);
}

// grid 1024 = 512 row-blocks x 2 key-splits; 256 thr = 4 waves = 2(feat) x 2(key-sub).
// Proven round-1 codegen (launch_bounds(256), ~80 VGPR, no spill); 4 blocks/CU.
// Writes UNNORMALIZED partial (scaled to combined in-block max) + per-row (m,l).
__global__ __launch_bounds__(256) void k2_attn(const int* __restrict__ adj,
                                               const unsigned short* __restrict__ hT,
                                               const float* __restrict__ s1,
                                               const float* __restrict__ s2,
                                               float* __restrict__ ml,
                                               float* __restrict__ p0,
                                               float* __restrict__ p1) {
    __shared__ float mlbuf[2][2][16];           // [m|l][wk][row]
    __shared__ float accbuf[2][16][132];        // [wn][row][feat] (+4 pad)

    const int tid = threadIdx.x;
    const int lane = tid & 63;
    const int wvi = tid >> 6;                   // 0..3
    const int wn = wvi & 1, wk = wvi >> 1;      // each 0..1
    const int lane15 = lane & 15, kg = lane >> 4, koff = kg * 8;
    const int split = (int)blockIdx.x >> 9;     // 0..1 (global key half)
    const int rowblk = (int)blockIdx.x & 511;
    const int row0 = rowblk * 16;
    const int mrow = row0 + lane15;
    const int fb = wn * 128;
    const int kbase = split * 4096 + wk * 2048; // each wave owns 2048 keys
    const float si = s1[mrow];
    const int* __restrict__ arow = adj + (size_t)mrow * N_ROWS;

    f32x4 acc[8];
#pragma unroll
    for (int nt = 0; nt < 8; ++nt) { f32x4 z = {0.f, 0.f, 0.f, 0.f}; acc[nt] = z; }
    float m_run = NEG_INF_F, l_run = 0.0f;

    i32x4 A0, A1, A2, A3, B0, B1, B2, B3;
    A0 = *(const i32x4*)(arow + kbase + koff);
    A1 = *(const i32x4*)(arow + kbase + koff + 4);
    A2 = *(const i32x4*)(arow + kbase + 32 + koff);
    A3 = *(const i32x4*)(arow + kbase + 32 + koff + 4);

#pragma unroll 1
    for (int it = 0; it < 16; ++it) {
        const int k0 = kbase + it * 128;
        {   // prefetch keys [k0+64, k0+128)
            const int kp = k0 + 64;
            B0 = *(const i32x4*)(arow + kp + koff);
            B1 = *(const i32x4*)(arow + kp + koff + 4);
            B2 = *(const i32x4*)(arow + kp + 32 + koff);
            B3 = *(const i32x4*)(arow + kp + 32 + koff + 4);
        }
        k2_step(A0, A1, A2, A3, k0, lane15, kg, koff, fb, si, hT, s2, acc, m_run, l_run);
        {   // prefetch next iteration's first half (clamped on last iter)
            const int kp = (it == 15) ? kbase : (k0 + 128);
            A0 = *(const i32x4*)(arow + kp + koff);
            A1 = *(const i32x4*)(arow + kp + koff + 4);
            A2 = *(const i32x4*)(arow + kp + 32 + koff);
            A3 = *(const i32x4*)(arow + kp + 32 + koff + 4);
        }
        k2_step(B0, B1, B2, B3, k0 + 64, lane15, kg, koff, fb, si, hT, s2, acc, m_run, l_run);
    }

    // ---- in-block combine across wk (flash merge, width 2) ----
    if (wn == 0 && kg == 0) {
        mlbuf[0][wk][lane15] = m_run;
        mlbuf[1][wk][lane15] = l_run;
    }
    __syncthreads();

    float myscale[4], mc[4], lc[4];
#pragma unroll
    for (int r = 0; r < 4; ++r) {
        const int dr = kg * 4 + r;              // D-layout row this lane owns
        const float m0 = mlbuf[0][0][dr], m1 = mlbuf[0][1][dr];
        const float ms = fmaxf(m0, m1);
        const float e0 = exp2f((m0 - ms) * LOG2E_F);
        const float e1 = exp2f((m1 - ms) * LOG2E_F);
        const float ls = e0 * mlbuf[1][0][dr] + e1 * mlbuf[1][1][dr];
        const float mo = mlbuf[0][wk][dr];      // own max
        myscale[r] = exp2f((mo - ms) * LOG2E_F);
        mc[r] = ms; lc[r] = ls;
    }
#pragma unroll
    for (int r = 0; r < 4; ++r)
#pragma unroll
        for (int nt = 0; nt < 8; ++nt) acc[nt][r] *= myscale[r];

    if (wk == 1) {
#pragma unroll
        for (int r = 0; r < 4; ++r)
#pragma unroll
            for (int nt = 0; nt < 8; ++nt)
                accbuf[wn][kg * 4 + r][nt * 16 + lane15] = acc[nt][r];
    }
    __syncthreads();

    if (wk == 0) {
        float* __restrict__ pdst = split ? p1 : p0;
#pragma unroll
        for (int r = 0; r < 4; ++r) {
            const int orow = row0 + kg * 4 + r;
            float* orow_p = pdst + (size_t)orow * F_DIM + fb + lane15;
#pragma unroll
            for (int nt = 0; nt < 8; ++nt)
                orow_p[nt * 16] = acc[nt][r] + accbuf[wn][kg * 4 + r][nt * 16 + lane15];
        }
        if (wn == 0 && lane15 == 0) {
#pragma unroll
            for (int r = 0; r < 4; ++r) {
                const int orow = row0 + kg * 4 + r;
                ml[(size_t)split * (N_ROWS * 2) + orow * 2 + 0] = mc[r];
                ml[(size_t)split * (N_ROWS * 2) + orow * 2 + 1] = lc[r];
            }
        }
    }
}

// ------------- Kernel 3: global split-K combine --------------------------
__global__ __launch_bounds__(256) void k3_merge(float* __restrict__ out,
                                                const float* __restrict__ p1,
                                                const float* __restrict__ ml) {
    const int idx = (int)blockIdx.x * 256 + threadIdx.x;   // 524288 threads
    const int row = idx >> 6, fc = (idx & 63) * 4;
    const float m0 = ml[row * 2], l0 = ml[row * 2 + 1];
    const float m1 = ml[N_ROWS * 2 + row * 2], l1 = ml[N_ROWS * 2 + row * 2 + 1];
    const float ms = fmaxf(m0, m1);
    const float w0 = exp2f((m0 - ms) * LOG2E_F);
    const float w1 = exp2f((m1 - ms) * LOG2E_F);
    const float inv = 1.0f / (w0 * l0 + w1 * l1);
    float* op = out + (size_t)row * F_DIM + fc;
    f32x4 v0 = *(const f32x4*)op;
    f32x4 v1 = *(const f32x4*)(p1 + (size_t)row * F_DIM + fc);
    f32x4 o;
#pragma unroll
    for (int j = 0; j < 4; ++j) o[j] = (w0 * v0[j] + w1 * v1[j]) * inv;
    *(f32x4*)op = o;
}

extern "C" void kernel_launch(void* const* d_in, const int* in_sizes, int n_in,
                              void* d_out, int out_size, void* d_ws, size_t ws_size,
                              hipStream_t stream) {
    (void)in_sizes; (void)n_in; (void)out_size; (void)ws_size;
    const float* x  = (const float*)d_in[0];
    const int*  adj = (const int*)d_in[1];
    const float* W  = (const float*)d_in[2];
    const float* a  = (const float*)d_in[3];
    float* out = (float*)d_out;
    char* ws = (char*)d_ws;
    unsigned short* hT = (unsigned short*)ws;                     // 4 MB  [256][8192] bf16
    float* s1 = (float*)(ws + (4 << 20));                         // 32 KB
    float* s2 = (float*)(ws + (4 << 20) + (32 << 10));            // 32 KB
    float* ml = (float*)(ws + (4 << 20) + (64 << 10));            // 128 KB [2][8192][2]
    float* h  = (float*)(ws + (4 << 20) + (192 << 10));           // 8 MB  [8192][256] f32
    float* p1 = h;                                                // overlays h (dead after k1b)

    k1_gemm<<<512, 256, 0, stream>>>(x, W, h, hT);
    k1b_s<<<256, 256, 0, stream>>>(h, a, s1, s2);
    k2_attn<<<1024, 256, 0, stream>>>(adj, hT, s1, s2, ml, out, p1);
    k3_merge<<<2048, 256, 0, stream>>>(out, p1, ml);
}